// Round 19
// baseline (133.395 us; speedup 1.0000x reference)
//
#include <hip/hip_runtime.h>
#include <stdint.h>

#define D_MODEL 1024
#define NH 16
#define DKH 64
#define BATCH 2
#define SEQ 2048
#define MROWS (BATCH * SEQ)   // 4096
#define KVBLK 128
#define NT (SEQ / KVBLK)      // 16
#define NK (D_MODEL / 32)     // 32 K-steps

typedef __bf16 bf16;
typedef __bf16 b16x8 __attribute__((ext_vector_type(8)));
typedef float f32x4 __attribute__((ext_vector_type(4)));
typedef float f32x16 __attribute__((ext_vector_type(16)));

#define C1 0.18033688011112042f  // 0.125 * log2(e), folded into Wq/bq

// async global->LDS, 16B per lane; LDS dest is wave-uniform base + lane*16 (HW)
__device__ __forceinline__ void gload_lds16(const void* g, void* l) {
  auto* gp = reinterpret_cast<const __attribute__((address_space(1))) uint32_t*>(
      reinterpret_cast<uintptr_t>(g));
  auto* lp = reinterpret_cast<__attribute__((address_space(3))) uint32_t*>(
      reinterpret_cast<uintptr_t>(l));
  __builtin_amdgcn_global_load_lds(gp, lp, 16, 0, 0);
}

__device__ __forceinline__ uint32_t cvtpk_bf16(float lo, float hi) {
  uint32_t r;
  asm("v_cvt_pk_bf16_f32 %0, %1, %2" : "=v"(r) : "v"(lo), "v"(hi));
  return r;
}
// x' = [x.lo | y.lo], y' = [x.hi | y.hi]  (s_nop guards VALU->permlane hazard)
__device__ __forceinline__ void perm32swap(uint32_t& x, uint32_t& y) {
  asm("s_nop 1\n\tv_permlane32_swap_b32 %0, %1\n\ts_nop 1" : "+v"(x), "+v"(y));
}
#if __has_builtin(__builtin_amdgcn_exp2f)
__device__ __forceinline__ float exp2_fast(float x) { return __builtin_amdgcn_exp2f(x); }
#else
__device__ __forceinline__ float exp2_fast(float x) { return exp2f(x); }
#endif

// ---------------- transpose-cast weights: W[K][N] f32 -> Wt[N][K] bf16 ----------------
// Wq additionally scaled by C1 (softmax scale folded into the Q projection).
__global__ void wtrans_kernel(const float* __restrict__ Wq, const float* __restrict__ Wk,
                              const float* __restrict__ Wv, const float* __restrict__ Wo,
                              bf16* __restrict__ Wqt, bf16* __restrict__ Wkt,
                              bf16* __restrict__ Wvt, bf16* __restrict__ Wot) {
  __shared__ float t[32][33];
  const float* W;
  bf16* Wt;
  switch (blockIdx.z) {
    case 0: W = Wq; Wt = Wqt; break;
    case 1: W = Wk; Wt = Wkt; break;
    case 2: W = Wv; Wt = Wvt; break;
    default: W = Wo; Wt = Wot; break;
  }
  const float scale = (blockIdx.z == 0) ? C1 : 1.0f;
  const int bx = blockIdx.x * 32, by = blockIdx.y * 32;
  const int tx = threadIdx.x, ty = threadIdx.y;
#pragma unroll
  for (int i = 0; i < 32; i += 8)
    t[ty + i][tx] = W[(size_t)(by + ty + i) * D_MODEL + bx + tx];
  __syncthreads();
#pragma unroll
  for (int i = 0; i < 32; i += 8)
    Wt[(size_t)(bx + ty + i) * D_MODEL + by + tx] = (bf16)(t[tx][ty + i] * scale);
}

// ---------------- gemm_qkv: 512 threads, 8 waves x (64x32) sub-tiles ----------------
// ROUND-18 PROVEN (8 waves/block -> 4 waves/SIMD). Same 2-barrier BK=32 structure,
// T14 A-prefetch. unroll 2 on the kt loop: opens the back-edge scheduling window so
// the A(kt+1) prefetch / B gload issue can overlap kt's MFMA cluster.
__global__ __launch_bounds__(512) void gemm_qkv_kernel(
    const float* __restrict__ q, const float* __restrict__ k, const float* __restrict__ v,
    const bf16* __restrict__ Wqt, const bf16* __restrict__ Wkt, const bf16* __restrict__ Wvt,
    const float* __restrict__ bq, const float* __restrict__ bk, const float* __restrict__ bv,
    bf16* __restrict__ Qo, bf16* __restrict__ Ko, bf16* __restrict__ Vo) {
  // 1-D grid, 768 blocks; decode keeps all 8 N-blocks of one (m,z) A-stripe on ONE XCD
  // (bid % 8 == (m + 32z) % 8), so A is fetched from HBM once and shared via L2.
  const int bid = blockIdx.x;
  const int n = bid / 96;
  const int g = bid % 96;
  const int m = g & 31;
  const int z = g >> 5;
  const float* A;
  const bf16* Bt;
  const float* bias;
  bf16* C;
  float bs = 1.0f;
  switch (z) {
    case 0: A = q; Bt = Wqt; bias = bq; C = Qo; bs = C1; break;
    case 1: A = k; Bt = Wkt; bias = bk; C = Ko; break;
    default: A = v; Bt = Wvt; bias = bv; C = Vo; break;
  }
  __shared__ __align__(16) bf16 As[128 * 32];
  __shared__ __align__(16) bf16 Bs[128 * 32];
  const int tid = threadIdx.x;
  const int w = tid >> 6, lane = tid & 63;
  const int wm = w >> 2, wn = w & 3;  // 2 x 4 wave grid; wave tile 64 rows x 32 cols
  const int mbase = m * 128, nbase = n * 128;
  const int srow = lane >> 2;
  const int scol = ((lane & 3) ^ ((lane >> 2) & 3)) * 8;  // pre-swizzled source col
  const int arow = tid >> 2, aslotL = tid & 3;            // f32-A staging (all 128 rows)
  f32x4 acc[4][2] = {};
  float4 f0, f1;  // A prefetch registers (one K-step ahead)
  {
    const float* src = A + (size_t)(mbase + arow) * D_MODEL + aslotL * 8;
    f0 = *(const float4*)(src);
    f1 = *(const float4*)(src + 4);
  }
#pragma unroll 2
  for (int kt = 0; kt < NK; ++kt) {
    __syncthreads();
    // B -> LDS: one gload issue per wave (8 waves x 16 rows = 128 rows)
    {
      const int r0 = w * 16;
      gload_lds16(Bt + (size_t)(nbase + r0 + srow) * D_MODEL + kt * 32 + scol,
                  (char*)Bs + r0 * 64);
    }
    // A: cvt regs loaded one step ago -> swizzled ds_write (counted vmcnt waits A only)
    {
      union { uint32_t u[4]; b16x8 v; } pk;
      pk.u[0] = cvtpk_bf16(f0.x, f0.y);
      pk.u[1] = cvtpk_bf16(f0.z, f0.w);
      pk.u[2] = cvtpk_bf16(f1.x, f1.y);
      pk.u[3] = cvtpk_bf16(f1.z, f1.w);
      *(b16x8*)(As + arow * 32 + ((aslotL ^ (arow & 3)) * 8)) = pk.v;
    }
    __syncthreads();
    // issue A loads for kt+1 (clamped; last-iter redundant re-load, unused)
    {
      const int ktn = (kt + 1 < NK) ? kt + 1 : kt;
      const float* src = A + (size_t)(mbase + arow) * D_MODEL + ktn * 32 + aslotL * 8;
      f0 = *(const float4*)(src);
      f1 = *(const float4*)(src + 4);
    }
    b16x8 af[4], bfr[2];
    const int l15 = lane & 15, hi = lane >> 4;
#pragma unroll
    for (int mm = 0; mm < 4; ++mm) {
      const int row = wm * 64 + mm * 16 + l15;
      af[mm] = *(const b16x8*)(As + row * 32 + ((hi ^ (row & 3)) * 8));
    }
#pragma unroll
    for (int nn = 0; nn < 2; ++nn) {
      const int row = wn * 32 + nn * 16 + l15;
      bfr[nn] = *(const b16x8*)(Bs + row * 32 + ((hi ^ (row & 3)) * 8));
    }
#pragma unroll
    for (int mm = 0; mm < 4; ++mm)
#pragma unroll
      for (int nn = 0; nn < 2; ++nn)
        acc[mm][nn] = __builtin_amdgcn_mfma_f32_16x16x32_bf16(af[mm], bfr[nn], acc[mm][nn], 0, 0, 0);
  }
  float bvv[2];
#pragma unroll
  for (int nn = 0; nn < 2; ++nn) bvv[nn] = bias[nbase + wn * 32 + nn * 16 + (lane & 15)] * bs;
  const int colb = nbase + wn * 32 + (lane & 15);
  const int rowb = mbase + wm * 64 + (lane >> 4) * 4;
#pragma unroll
  for (int mm = 0; mm < 4; ++mm)
#pragma unroll
    for (int nn = 0; nn < 2; ++nn)
#pragma unroll
      for (int r = 0; r < 4; ++r)
        C[(size_t)(rowb + mm * 16 + r) * D_MODEL + colb + nn * 16] =
            (bf16)(acc[mm][nn][r] + bvv[nn]);
}

// ---------------- gemm_out: 512 threads, 8 waves, each owns a 64x32 sub-tile ------------
// ROUND-15 PROVEN. unroll 2 opens the back-edge scheduling window.
__global__ __launch_bounds__(512) void gemm_out_kernel(
    const bf16* __restrict__ Aatt, const bf16* __restrict__ Wot,
    const float* __restrict__ bo, float* __restrict__ out) {
  __shared__ __align__(16) bf16 As[128 * 32];
  __shared__ __align__(16) bf16 Bs[128 * 32];
  const int tid = threadIdx.x;
  const int w = tid >> 6, lane = tid & 63;
  const int wm = w >> 2, wn = w & 3;  // 2 x 4 wave grid; wave tile 64 rows x 32 cols
  const int bid = blockIdx.x;
  const int mblk = bid & 31, nblk = bid >> 5;  // bid%8 == m%8 -> A-stripe XCD locality
  const int mbase = mblk * 128, nbase = nblk * 128;
  const int srow = lane >> 2;
  const int scol = ((lane & 3) ^ ((lane >> 2) & 3)) * 8;  // pre-swizzled source col
  f32x4 acc[4][2] = {};
#pragma unroll 2
  for (int kt = 0; kt < NK; ++kt) {
    __syncthreads();
    {
      const int r0 = w * 16;  // 8 waves x 16 rows = 128 rows
      gload_lds16(Aatt + (size_t)(mbase + r0 + srow) * D_MODEL + kt * 32 + scol,
                  (char*)As + r0 * 64);
      gload_lds16(Wot + (size_t)(nbase + r0 + srow) * D_MODEL + kt * 32 + scol,
                  (char*)Bs + r0 * 64);
    }
    __syncthreads();
    b16x8 af[4], bfr[2];
    const int l15 = lane & 15, hi = lane >> 4;
#pragma unroll
    for (int m = 0; m < 4; ++m) {
      const int row = wm * 64 + m * 16 + l15;
      af[m] = *(const b16x8*)(As + row * 32 + ((hi ^ (row & 3)) * 8));
    }
#pragma unroll
    for (int n = 0; n < 2; ++n) {
      const int row = wn * 32 + n * 16 + l15;
      bfr[n] = *(const b16x8*)(Bs + row * 32 + ((hi ^ (row & 3)) * 8));
    }
#pragma unroll
    for (int m = 0; m < 4; ++m)
#pragma unroll
      for (int n = 0; n < 2; ++n)
        acc[m][n] = __builtin_amdgcn_mfma_f32_16x16x32_bf16(af[m], bfr[n], acc[m][n], 0, 0, 0);
  }
  float bv[2];
#pragma unroll
  for (int n = 0; n < 2; ++n) bv[n] = bo[nbase + wn * 32 + n * 16 + (lane & 15)];
  const int colb = nbase + wn * 32 + (lane & 15);
  const int rowb = mbase + wm * 64 + (lane >> 4) * 4;
#pragma unroll
  for (int m = 0; m < 4; ++m)
#pragma unroll
    for (int n = 0; n < 2; ++n)
#pragma unroll
      for (int r = 0; r < 4; ++r)
        out[(size_t)(rowb + m * 16 + r) * D_MODEL + colb + n * 16] = acc[m][n][r] + bv[n];
}

// ---------------- flash attention, swapped-QK^T, 32x32x16 MFMA ----------------
// ROUND-9 PROVEN STRUCTURE. unroll 2 on the kt loop: lets the scheduler hoist the
// V(t+1) global loads (no barrier between PV(t) and them) under PV(t)'s MFMA cluster —
// the T14 overlap achieved purely by widening the scheduling window, no reordering.
__global__ __launch_bounds__(256) void attn_kernel(
    const bf16* __restrict__ Qg, const bf16* __restrict__ Kg,
    const bf16* __restrict__ Vg, bf16* __restrict__ Og) {
  // Ks [128][64] bf16 (16384 B) + Vt [64][136] bf16 (17408 B) = 33792 B
  __shared__ __align__(16) char smem[16384 + 17408];
  bf16* Ks = (bf16*)smem;
  bf16* Vt = (bf16*)(smem + 16384);
  uint32_t* Vt32 = (uint32_t*)Vt;
  const int tid = threadIdx.x, w = tid >> 6, lane = tid & 63;
  const int l31 = lane & 31, b5 = lane >> 5;
  // XCD-aware swizzle: cluster the 16 q-blocks of one (b,h) on one XCD (512 % 8 == 0)
  int lin = blockIdx.y * gridDim.x + blockIdx.x;
  lin = (lin & 7) * 64 + (lin >> 3);
  const int bx = lin & 15, bh = lin >> 4;
  const size_t base = (size_t)(bh >> 4) * SEQ * D_MODEL + (size_t)(bh & 15) * DKH;
  const int qbase = bx * 128;

  // Q fragments (B-operand): col = q = l31, contraction d = ds*16 + 8*b5 + j
  b16x8 qf[4];
#pragma unroll
  for (int ds = 0; ds < 4; ++ds)
    qf[ds] = *(const b16x8*)(Qg + base + (size_t)(qbase + w * 32 + l31) * D_MODEL +
                             ds * 16 + b5 * 8);

  f32x16 oacc[2] = {};
  float rsp[4] = {0.f, 0.f, 0.f, 0.f};  // per-lane l partials, accumulated across tiles
  const int ksl = (lane & 7) ^ (lane >> 3);  // pre-swizzled K source slot
  const bf16* vbase = Vg + base + (size_t)(2 * lane) * D_MODEL + w * 8;
  union U8 { b16x8 h; uint16_t u[8]; };

#pragma unroll 2
  for (int kt = 0; kt < NT; ++kt) {
    // V loads for THIS tile issue before barrier #1 (latency covered by barrier wait)
    const bf16* vsrc = vbase + (size_t)kt * KVBLK * D_MODEL;
    b16x8 va0 = *(const b16x8*)(vsrc);
    b16x8 va1 = *(const b16x8*)(vsrc + D_MODEL);
    b16x8 vb0 = *(const b16x8*)(vsrc + 32);
    b16x8 vb1 = *(const b16x8*)(vsrc + D_MODEL + 32);
    __syncthreads();
    // K -> LDS, swizzled source, linear dest (phys slot = logical ^ (row&7))
#pragma unroll
    for (int i = 0; i < 4; ++i) {
      const int r0 = (i * 4 + w) * 8;
      gload_lds16(Kg + base + (size_t)(kt * KVBLK + r0 + (lane >> 3)) * D_MODEL + ksl * 8,
                  (char*)Ks + r0 * 128);
    }
    // V transpose: packed b32 writes, stride 68 words (136 bf16, 272 B, aligned)
    U8 ua0{va0}, ua1{va1}, ub0{vb0}, ub1{vb1};
#pragma unroll
    for (int j = 0; j < 8; ++j) {
      Vt32[(w * 8 + j) * 68 + lane] = (uint32_t)ua0.u[j] | ((uint32_t)ua1.u[j] << 16);
      Vt32[(w * 8 + 32 + j) * 68 + lane] = (uint32_t)ub0.u[j] | ((uint32_t)ub1.u[j] << 16);
    }
    __syncthreads();

    // ---- QK^T swapped: sacc[ch] = S^T[k = ch*32 + (r&3)+8*(r>>2)+4*b5][q = l31] ----
    f32x16 sacc[4] = {};
    __builtin_amdgcn_s_setprio(1);
#pragma unroll
    for (int ds = 0; ds < 4; ++ds) {
#pragma unroll
      for (int ch = 0; ch < 4; ++ch) {
        const int krow = ch * 32 + l31;
        const int sl = (ds * 2 + b5) ^ (krow & 7);
        const b16x8 kf = *(const b16x8*)(Ks + krow * 64 + sl * 8);
        sacc[ch] = __builtin_amdgcn_mfma_f32_32x32x16_bf16(kf, qf[ds], sacc[ch], 0, 0, 0);
      }
    }
    __builtin_amdgcn_s_setprio(0);

    // ---- softmax numerator, log2 domain, fixed shift m=0 ----
#pragma unroll
    for (int ch = 0; ch < 4; ++ch)
#pragma unroll
      for (int r = 0; r < 16; ++r) {
        const float p = exp2_fast(sacc[ch][r]);
        sacc[ch][r] = p;
        rsp[r & 3] += p;
      }

    // ---- pack P^T -> PV B-fragments ----
    b16x8 pb[8];
#pragma unroll
    for (int ch = 0; ch < 4; ++ch) {
#pragma unroll
      for (int cc = 0; cc < 2; ++cc) {
        uint32_t x0 = cvtpk_bf16(sacc[ch][cc * 8 + 0], sacc[ch][cc * 8 + 1]);
        uint32_t y0 = cvtpk_bf16(sacc[ch][cc * 8 + 4], sacc[ch][cc * 8 + 5]);
        uint32_t x1 = cvtpk_bf16(sacc[ch][cc * 8 + 2], sacc[ch][cc * 8 + 3]);
        uint32_t y1 = cvtpk_bf16(sacc[ch][cc * 8 + 6], sacc[ch][cc * 8 + 7]);
        perm32swap(x0, y0);
        perm32swap(x1, y1);
        union { uint32_t u[4]; b16x8 v; } pk;
        pk.u[0] = x0; pk.u[1] = x1; pk.u[2] = y0; pk.u[3] = y1;
        pb[ch * 2 + cc] = pk.v;
      }
    }

    // ---- PV: O^T[d][q] += V^T frags (A) x P^T frags (B), stride-136 Vt ----
    __builtin_amdgcn_s_setprio(1);
#pragma unroll
    for (int kc = 0; kc < 8; ++kc) {
#pragma unroll
      for (int n = 0; n < 2; ++n) {
        const int d = n * 32 + l31;
        const b16x8 vf = *(const b16x8*)(Vt + d * 136 + kc * 16 + b5 * 8);
        oacc[n] = __builtin_amdgcn_mfma_f32_32x32x16_bf16(vf, pb[kc], oacc[n], 0, 0, 0);
      }
    }
    __builtin_amdgcn_s_setprio(0);
  }

  // ---- epilogue: single cross-half l reduce, normalize, transpose via reused LDS ----
  float l_run = (rsp[0] + rsp[1]) + (rsp[2] + rsp[3]);
  l_run += __shfl_xor(l_run, 32);
  const float inv = 1.f / l_run;
  __syncthreads();
  uint32_t* Otw = (uint32_t*)smem + w * (32 * 36);
#pragma unroll
  for (int n = 0; n < 2; ++n)
#pragma unroll
    for (int r2 = 0; r2 < 4; ++r2)
#pragma unroll
      for (int rp = 0; rp < 2; ++rp) {
        uint32_t pk = cvtpk_bf16(oacc[n][4 * r2 + 2 * rp] * inv,
                                 oacc[n][4 * r2 + 2 * rp + 1] * inv);
        Otw[l31 * 36 + n * 16 + r2 * 4 + b5 * 2 + rp] = pk;
      }
  __syncthreads();
  const int q = lane >> 1, half = lane & 1;
  const uint32_t* src = (uint32_t*)smem + w * (32 * 36) + q * 36 + half * 16;
  bf16* dst = Og + base + (size_t)(qbase + w * 32 + q) * D_MODEL + half * 32;
#pragma unroll
  for (int t = 0; t < 4; ++t)
    *(b16x8*)(dst + t * 8) = *(const b16x8*)(src + t * 4);
}

// ---------------- launch ----------------
extern "C" void kernel_launch(void* const* d_in, const int* in_sizes, int n_in,
                              void* d_out, int out_size, void* d_ws, size_t ws_size,
                              hipStream_t stream) {
  const float* query = (const float*)d_in[0];
  const float* key = (const float*)d_in[1];
  const float* value = (const float*)d_in[2];
  const float* Wq = (const float*)d_in[3];
  const float* bq = (const float*)d_in[4];
  const float* Wk = (const float*)d_in[5];
  const float* bk = (const float*)d_in[6];
  const float* Wv = (const float*)d_in[7];
  const float* bv = (const float*)d_in[8];
  const float* Wo = (const float*)d_in[9];
  const float* bo = (const float*)d_in[10];
  float* out = (float*)d_out;

  char* ws = (char*)d_ws;
  const size_t SZ_T = (size_t)MROWS * D_MODEL * sizeof(bf16);    // 8 MB
  const size_t SZ_W = (size_t)D_MODEL * D_MODEL * sizeof(bf16);  // 2 MB
  bf16* Qb  = (bf16*)(ws + 0 * SZ_T);
  bf16* Kb  = (bf16*)(ws + 1 * SZ_T);
  bf16* Vb  = (bf16*)(ws + 2 * SZ_T);
  bf16* Att = (bf16*)(ws + 3 * SZ_T);
  bf16* Wqt = (bf16*)(ws + 4 * SZ_T + 0 * SZ_W);
  bf16* Wkt = (bf16*)(ws + 4 * SZ_T + 1 * SZ_W);
  bf16* Wvt = (bf16*)(ws + 4 * SZ_T + 2 * SZ_W);
  bf16* Wot = (bf16*)(ws + 4 * SZ_T + 3 * SZ_W);

  wtrans_kernel<<<dim3(32, 32, 4), dim3(32, 8), 0, stream>>>(Wq, Wk, Wv, Wo, Wqt, Wkt, Wvt, Wot);
  gemm_qkv_kernel<<<dim3(768, 1, 1), 512, 0, stream>>>(
      query, key, value, Wqt, Wkt, Wvt, bq, bk, bv, Qb, Kb, Vb);
  attn_kernel<<<dim3(SEQ / 128, BATCH * NH), 256, 0, stream>>>(Qb, Kb, Vb, Att);
  gemm_out_kernel<<<dim3(256, 1, 1), 512, 0, stream>>>(Att, Wot, bo, out);
}

// Round 20
// 126.647 us; speedup vs baseline: 1.0533x; 1.0533x over previous
//
#include <hip/hip_runtime.h>
#include <stdint.h>

#define D_MODEL 1024
#define NH 16
#define DKH 64
#define BATCH 2
#define SEQ 2048
#define MROWS (BATCH * SEQ)   // 4096
#define KVBLK 128
#define NT (SEQ / KVBLK)      // 16
#define NK (D_MODEL / 32)     // 32 K-steps

typedef __bf16 bf16;
typedef __bf16 b16x8 __attribute__((ext_vector_type(8)));
typedef float f32x4 __attribute__((ext_vector_type(4)));
typedef float f32x16 __attribute__((ext_vector_type(16)));

#define C1 0.18033688011112042f  // 0.125 * log2(e), folded into Wq/bq

// async global->LDS, 16B per lane; LDS dest is wave-uniform base + lane*16 (HW)
__device__ __forceinline__ void gload_lds16(const void* g, void* l) {
  auto* gp = reinterpret_cast<const __attribute__((address_space(1))) uint32_t*>(
      reinterpret_cast<uintptr_t>(g));
  auto* lp = reinterpret_cast<__attribute__((address_space(3))) uint32_t*>(
      reinterpret_cast<uintptr_t>(l));
  __builtin_amdgcn_global_load_lds(gp, lp, 16, 0, 0);
}

__device__ __forceinline__ uint32_t cvtpk_bf16(float lo, float hi) {
  uint32_t r;
  asm("v_cvt_pk_bf16_f32 %0, %1, %2" : "=v"(r) : "v"(lo), "v"(hi));
  return r;
}
// x' = [x.lo | y.lo], y' = [x.hi | y.hi]  (s_nop guards VALU->permlane hazard)
__device__ __forceinline__ void perm32swap(uint32_t& x, uint32_t& y) {
  asm("s_nop 1\n\tv_permlane32_swap_b32 %0, %1\n\ts_nop 1" : "+v"(x), "+v"(y));
}
#if __has_builtin(__builtin_amdgcn_exp2f)
__device__ __forceinline__ float exp2_fast(float x) { return __builtin_amdgcn_exp2f(x); }
#else
__device__ __forceinline__ float exp2_fast(float x) { return exp2f(x); }
#endif

// ---------------- transpose-cast weights: W[K][N] f32 -> Wt[N][K] bf16 ----------------
// Wq additionally scaled by C1 (softmax scale folded into the Q projection).
__global__ void wtrans_kernel(const float* __restrict__ Wq, const float* __restrict__ Wk,
                              const float* __restrict__ Wv, const float* __restrict__ Wo,
                              bf16* __restrict__ Wqt, bf16* __restrict__ Wkt,
                              bf16* __restrict__ Wvt, bf16* __restrict__ Wot) {
  __shared__ float t[32][33];
  const float* W;
  bf16* Wt;
  switch (blockIdx.z) {
    case 0: W = Wq; Wt = Wqt; break;
    case 1: W = Wk; Wt = Wkt; break;
    case 2: W = Wv; Wt = Wvt; break;
    default: W = Wo; Wt = Wot; break;
  }
  const float scale = (blockIdx.z == 0) ? C1 : 1.0f;
  const int bx = blockIdx.x * 32, by = blockIdx.y * 32;
  const int tx = threadIdx.x, ty = threadIdx.y;
#pragma unroll
  for (int i = 0; i < 32; i += 8)
    t[ty + i][tx] = W[(size_t)(by + ty + i) * D_MODEL + bx + tx];
  __syncthreads();
#pragma unroll
  for (int i = 0; i < 32; i += 8)
    Wt[(size_t)(bx + ty + i) * D_MODEL + by + tx] = (bf16)(t[tx][ty + i] * scale);
}

// ---------------- gemm_qkv: 512 threads, 8 waves x (64x32) sub-tiles ----------------
// ROUND-18 PROVEN (8 waves/block -> 4 waves/SIMD, 2-barrier BK=32, T14 A-prefetch).
// unroll stays at 1: r19's unroll-2 collapsed VGPR to 36 and regressed (-15%).
__global__ __launch_bounds__(512) void gemm_qkv_kernel(
    const float* __restrict__ q, const float* __restrict__ k, const float* __restrict__ v,
    const bf16* __restrict__ Wqt, const bf16* __restrict__ Wkt, const bf16* __restrict__ Wvt,
    const float* __restrict__ bq, const float* __restrict__ bk, const float* __restrict__ bv,
    bf16* __restrict__ Qo, bf16* __restrict__ Ko, bf16* __restrict__ Vo) {
  // 1-D grid, 768 blocks; decode keeps all 8 N-blocks of one (m,z) A-stripe on ONE XCD
  // (bid % 8 == (m + 32z) % 8), so A is fetched from HBM once and shared via L2.
  const int bid = blockIdx.x;
  const int n = bid / 96;
  const int g = bid % 96;
  const int m = g & 31;
  const int z = g >> 5;
  const float* A;
  const bf16* Bt;
  const float* bias;
  bf16* C;
  float bs = 1.0f;
  switch (z) {
    case 0: A = q; Bt = Wqt; bias = bq; C = Qo; bs = C1; break;
    case 1: A = k; Bt = Wkt; bias = bk; C = Ko; break;
    default: A = v; Bt = Wvt; bias = bv; C = Vo; break;
  }
  __shared__ __align__(16) bf16 As[128 * 32];
  __shared__ __align__(16) bf16 Bs[128 * 32];
  const int tid = threadIdx.x;
  const int w = tid >> 6, lane = tid & 63;
  const int wm = w >> 2, wn = w & 3;  // 2 x 4 wave grid; wave tile 64 rows x 32 cols
  const int mbase = m * 128, nbase = n * 128;
  const int srow = lane >> 2;
  const int scol = ((lane & 3) ^ ((lane >> 2) & 3)) * 8;  // pre-swizzled source col
  const int arow = tid >> 2, aslotL = tid & 3;            // f32-A staging (all 128 rows)
  f32x4 acc[4][2] = {};
  float4 f0, f1;  // A prefetch registers (one K-step ahead)
  {
    const float* src = A + (size_t)(mbase + arow) * D_MODEL + aslotL * 8;
    f0 = *(const float4*)(src);
    f1 = *(const float4*)(src + 4);
  }
#pragma unroll 1
  for (int kt = 0; kt < NK; ++kt) {
    __syncthreads();
    // B -> LDS: one gload issue per wave (8 waves x 16 rows = 128 rows)
    {
      const int r0 = w * 16;
      gload_lds16(Bt + (size_t)(nbase + r0 + srow) * D_MODEL + kt * 32 + scol,
                  (char*)Bs + r0 * 64);
    }
    // A: cvt regs loaded one step ago -> swizzled ds_write
    {
      union { uint32_t u[4]; b16x8 v; } pk;
      pk.u[0] = cvtpk_bf16(f0.x, f0.y);
      pk.u[1] = cvtpk_bf16(f0.z, f0.w);
      pk.u[2] = cvtpk_bf16(f1.x, f1.y);
      pk.u[3] = cvtpk_bf16(f1.z, f1.w);
      *(b16x8*)(As + arow * 32 + ((aslotL ^ (arow & 3)) * 8)) = pk.v;
    }
    __syncthreads();
    // issue A loads for kt+1 (clamped; last-iter redundant re-load, unused)
    {
      const int ktn = (kt + 1 < NK) ? kt + 1 : kt;
      const float* src = A + (size_t)(mbase + arow) * D_MODEL + ktn * 32 + aslotL * 8;
      f0 = *(const float4*)(src);
      f1 = *(const float4*)(src + 4);
    }
    b16x8 af[4], bfr[2];
    const int l15 = lane & 15, hi = lane >> 4;
#pragma unroll
    for (int mm = 0; mm < 4; ++mm) {
      const int row = wm * 64 + mm * 16 + l15;
      af[mm] = *(const b16x8*)(As + row * 32 + ((hi ^ (row & 3)) * 8));
    }
#pragma unroll
    for (int nn = 0; nn < 2; ++nn) {
      const int row = wn * 32 + nn * 16 + l15;
      bfr[nn] = *(const b16x8*)(Bs + row * 32 + ((hi ^ (row & 3)) * 8));
    }
#pragma unroll
    for (int mm = 0; mm < 4; ++mm)
#pragma unroll
      for (int nn = 0; nn < 2; ++nn)
        acc[mm][nn] = __builtin_amdgcn_mfma_f32_16x16x32_bf16(af[mm], bfr[nn], acc[mm][nn], 0, 0, 0);
  }
  float bvv[2];
#pragma unroll
  for (int nn = 0; nn < 2; ++nn) bvv[nn] = bias[nbase + wn * 32 + nn * 16 + (lane & 15)] * bs;
  const int colb = nbase + wn * 32 + (lane & 15);
  const int rowb = mbase + wm * 64 + (lane >> 4) * 4;
#pragma unroll
  for (int mm = 0; mm < 4; ++mm)
#pragma unroll
    for (int nn = 0; nn < 2; ++nn)
#pragma unroll
      for (int r = 0; r < 4; ++r)
        C[(size_t)(rowb + mm * 16 + r) * D_MODEL + colb + nn * 16] =
            (bf16)(acc[mm][nn][r] + bvv[nn]);
}

// ---------------- gemm_out: 512 threads, 8 waves, each owns a 64x32 sub-tile ------------
// ROUND-15 PROVEN (2 waves/SIMD vs prior 1). Same 2-barrier BK=32 structure.
__global__ __launch_bounds__(512) void gemm_out_kernel(
    const bf16* __restrict__ Aatt, const bf16* __restrict__ Wot,
    const float* __restrict__ bo, float* __restrict__ out) {
  __shared__ __align__(16) bf16 As[128 * 32];
  __shared__ __align__(16) bf16 Bs[128 * 32];
  const int tid = threadIdx.x;
  const int w = tid >> 6, lane = tid & 63;
  const int wm = w >> 2, wn = w & 3;  // 2 x 4 wave grid; wave tile 64 rows x 32 cols
  const int bid = blockIdx.x;
  const int mblk = bid & 31, nblk = bid >> 5;  // bid%8 == m%8 -> A-stripe XCD locality
  const int mbase = mblk * 128, nbase = nblk * 128;
  const int srow = lane >> 2;
  const int scol = ((lane & 3) ^ ((lane >> 2) & 3)) * 8;  // pre-swizzled source col
  f32x4 acc[4][2] = {};
#pragma unroll 1
  for (int kt = 0; kt < NK; ++kt) {
    __syncthreads();
    {
      const int r0 = w * 16;  // 8 waves x 16 rows = 128 rows
      gload_lds16(Aatt + (size_t)(mbase + r0 + srow) * D_MODEL + kt * 32 + scol,
                  (char*)As + r0 * 64);
      gload_lds16(Wot + (size_t)(nbase + r0 + srow) * D_MODEL + kt * 32 + scol,
                  (char*)Bs + r0 * 64);
    }
    __syncthreads();
    b16x8 af[4], bfr[2];
    const int l15 = lane & 15, hi = lane >> 4;
#pragma unroll
    for (int m = 0; m < 4; ++m) {
      const int row = wm * 64 + m * 16 + l15;
      af[m] = *(const b16x8*)(As + row * 32 + ((hi ^ (row & 3)) * 8));
    }
#pragma unroll
    for (int n = 0; n < 2; ++n) {
      const int row = wn * 32 + n * 16 + l15;
      bfr[n] = *(const b16x8*)(Bs + row * 32 + ((hi ^ (row & 3)) * 8));
    }
#pragma unroll
    for (int m = 0; m < 4; ++m)
#pragma unroll
      for (int n = 0; n < 2; ++n)
        acc[m][n] = __builtin_amdgcn_mfma_f32_16x16x32_bf16(af[m], bfr[n], acc[m][n], 0, 0, 0);
  }
  float bv[2];
#pragma unroll
  for (int n = 0; n < 2; ++n) bv[n] = bo[nbase + wn * 32 + n * 16 + (lane & 15)];
  const int colb = nbase + wn * 32 + (lane & 15);
  const int rowb = mbase + wm * 64 + (lane >> 4) * 4;
#pragma unroll
  for (int m = 0; m < 4; ++m)
#pragma unroll
    for (int n = 0; n < 2; ++n)
#pragma unroll
      for (int r = 0; r < 4; ++r)
        out[(size_t)(rowb + m * 16 + r) * D_MODEL + colb + n * 16] = acc[m][n][r] + bv[n];
}

// ---------------- flash attention, swapped-QK^T, 32x32x16 MFMA ----------------
// ROUND-9 PROVEN STRUCTURE, byte-exact (57.5 µs). Two barriers/tile, single K/V buffer,
// Vt stride 136, log2-domain no-max softmax, per-lane l accumulation. unroll stays 1.
__global__ __launch_bounds__(256) void attn_kernel(
    const bf16* __restrict__ Qg, const bf16* __restrict__ Kg,
    const bf16* __restrict__ Vg, bf16* __restrict__ Og) {
  // Ks [128][64] bf16 (16384 B) + Vt [64][136] bf16 (17408 B) = 33792 B
  __shared__ __align__(16) char smem[16384 + 17408];
  bf16* Ks = (bf16*)smem;
  bf16* Vt = (bf16*)(smem + 16384);
  uint32_t* Vt32 = (uint32_t*)Vt;
  const int tid = threadIdx.x, w = tid >> 6, lane = tid & 63;
  const int l31 = lane & 31, b5 = lane >> 5;
  // XCD-aware swizzle: cluster the 16 q-blocks of one (b,h) on one XCD (512 % 8 == 0)
  int lin = blockIdx.y * gridDim.x + blockIdx.x;
  lin = (lin & 7) * 64 + (lin >> 3);
  const int bx = lin & 15, bh = lin >> 4;
  const size_t base = (size_t)(bh >> 4) * SEQ * D_MODEL + (size_t)(bh & 15) * DKH;
  const int qbase = bx * 128;

  // Q fragments (B-operand): col = q = l31, contraction d = ds*16 + 8*b5 + j
  b16x8 qf[4];
#pragma unroll
  for (int ds = 0; ds < 4; ++ds)
    qf[ds] = *(const b16x8*)(Qg + base + (size_t)(qbase + w * 32 + l31) * D_MODEL +
                             ds * 16 + b5 * 8);

  f32x16 oacc[2] = {};
  float rsp[4] = {0.f, 0.f, 0.f, 0.f};  // per-lane l partials, accumulated across tiles
  const int ksl = (lane & 7) ^ (lane >> 3);  // pre-swizzled K source slot
  const bf16* vbase = Vg + base + (size_t)(2 * lane) * D_MODEL + w * 8;
  union U8 { b16x8 h; uint16_t u[8]; };

#pragma unroll 1
  for (int kt = 0; kt < NT; ++kt) {
    // V loads for THIS tile issue before barrier #1 (latency covered by barrier wait)
    const bf16* vsrc = vbase + (size_t)kt * KVBLK * D_MODEL;
    b16x8 va0 = *(const b16x8*)(vsrc);
    b16x8 va1 = *(const b16x8*)(vsrc + D_MODEL);
    b16x8 vb0 = *(const b16x8*)(vsrc + 32);
    b16x8 vb1 = *(const b16x8*)(vsrc + D_MODEL + 32);
    __syncthreads();
    // K -> LDS, swizzled source, linear dest (phys slot = logical ^ (row&7))
#pragma unroll
    for (int i = 0; i < 4; ++i) {
      const int r0 = (i * 4 + w) * 8;
      gload_lds16(Kg + base + (size_t)(kt * KVBLK + r0 + (lane >> 3)) * D_MODEL + ksl * 8,
                  (char*)Ks + r0 * 128);
    }
    // V transpose: packed b32 writes, stride 68 words (136 bf16, 272 B, aligned)
    U8 ua0{va0}, ua1{va1}, ub0{vb0}, ub1{vb1};
#pragma unroll
    for (int j = 0; j < 8; ++j) {
      Vt32[(w * 8 + j) * 68 + lane] = (uint32_t)ua0.u[j] | ((uint32_t)ua1.u[j] << 16);
      Vt32[(w * 8 + 32 + j) * 68 + lane] = (uint32_t)ub0.u[j] | ((uint32_t)ub1.u[j] << 16);
    }
    __syncthreads();

    // ---- QK^T swapped: sacc[ch] = S^T[k = ch*32 + (r&3)+8*(r>>2)+4*b5][q = l31] ----
    f32x16 sacc[4] = {};
    __builtin_amdgcn_s_setprio(1);
#pragma unroll
    for (int ds = 0; ds < 4; ++ds) {
#pragma unroll
      for (int ch = 0; ch < 4; ++ch) {
        const int krow = ch * 32 + l31;
        const int sl = (ds * 2 + b5) ^ (krow & 7);
        const b16x8 kf = *(const b16x8*)(Ks + krow * 64 + sl * 8);
        sacc[ch] = __builtin_amdgcn_mfma_f32_32x32x16_bf16(kf, qf[ds], sacc[ch], 0, 0, 0);
      }
    }
    __builtin_amdgcn_s_setprio(0);

    // ---- softmax numerator, log2 domain, fixed shift m=0 ----
#pragma unroll
    for (int ch = 0; ch < 4; ++ch)
#pragma unroll
      for (int r = 0; r < 16; ++r) {
        const float p = exp2_fast(sacc[ch][r]);
        sacc[ch][r] = p;
        rsp[r & 3] += p;
      }

    // ---- pack P^T -> PV B-fragments ----
    b16x8 pb[8];
#pragma unroll
    for (int ch = 0; ch < 4; ++ch) {
#pragma unroll
      for (int cc = 0; cc < 2; ++cc) {
        uint32_t x0 = cvtpk_bf16(sacc[ch][cc * 8 + 0], sacc[ch][cc * 8 + 1]);
        uint32_t y0 = cvtpk_bf16(sacc[ch][cc * 8 + 4], sacc[ch][cc * 8 + 5]);
        uint32_t x1 = cvtpk_bf16(sacc[ch][cc * 8 + 2], sacc[ch][cc * 8 + 3]);
        uint32_t y1 = cvtpk_bf16(sacc[ch][cc * 8 + 6], sacc[ch][cc * 8 + 7]);
        perm32swap(x0, y0);
        perm32swap(x1, y1);
        union { uint32_t u[4]; b16x8 v; } pk;
        pk.u[0] = x0; pk.u[1] = x1; pk.u[2] = y0; pk.u[3] = y1;
        pb[ch * 2 + cc] = pk.v;
      }
    }

    // ---- PV: O^T[d][q] += V^T frags (A) x P^T frags (B), stride-136 Vt ----
    __builtin_amdgcn_s_setprio(1);
#pragma unroll
    for (int kc = 0; kc < 8; ++kc) {
#pragma unroll
      for (int n = 0; n < 2; ++n) {
        const int d = n * 32 + l31;
        const b16x8 vf = *(const b16x8*)(Vt + d * 136 + kc * 16 + b5 * 8);
        oacc[n] = __builtin_amdgcn_mfma_f32_32x32x16_bf16(vf, pb[kc], oacc[n], 0, 0, 0);
      }
    }
    __builtin_amdgcn_s_setprio(0);
  }

  // ---- epilogue: single cross-half l reduce, normalize, transpose via reused LDS ----
  float l_run = (rsp[0] + rsp[1]) + (rsp[2] + rsp[3]);
  l_run += __shfl_xor(l_run, 32);
  const float inv = 1.f / l_run;
  __syncthreads();
  uint32_t* Otw = (uint32_t*)smem + w * (32 * 36);
#pragma unroll
  for (int n = 0; n < 2; ++n)
#pragma unroll
    for (int r2 = 0; r2 < 4; ++r2)
#pragma unroll
      for (int rp = 0; rp < 2; ++rp) {
        uint32_t pk = cvtpk_bf16(oacc[n][4 * r2 + 2 * rp] * inv,
                                 oacc[n][4 * r2 + 2 * rp + 1] * inv);
        Otw[l31 * 36 + n * 16 + r2 * 4 + b5 * 2 + rp] = pk;
      }
  __syncthreads();
  const int q = lane >> 1, half = lane & 1;
  const uint32_t* src = (uint32_t*)smem + w * (32 * 36) + q * 36 + half * 16;
  bf16* dst = Og + base + (size_t)(qbase + w * 32 + q) * D_MODEL + half * 32;
#pragma unroll
  for (int t = 0; t < 4; ++t)
    *(b16x8*)(dst + t * 8) = *(const b16x8*)(src + t * 4);
}

// ---------------- launch ----------------
extern "C" void kernel_launch(void* const* d_in, const int* in_sizes, int n_in,
                              void* d_out, int out_size, void* d_ws, size_t ws_size,
                              hipStream_t stream) {
  const float* query = (const float*)d_in[0];
  const float* key = (const float*)d_in[1];
  const float* value = (const float*)d_in[2];
  const float* Wq = (const float*)d_in[3];
  const float* bq = (const float*)d_in[4];
  const float* Wk = (const float*)d_in[5];
  const float* bk = (const float*)d_in[6];
  const float* Wv = (const float*)d_in[7];
  const float* bv = (const float*)d_in[8];
  const float* Wo = (const float*)d_in[9];
  const float* bo = (const float*)d_in[10];
  float* out = (float*)d_out;

  char* ws = (char*)d_ws;
  const size_t SZ_T = (size_t)MROWS * D_MODEL * sizeof(bf16);    // 8 MB
  const size_t SZ_W = (size_t)D_MODEL * D_MODEL * sizeof(bf16);  // 2 MB
  bf16* Qb  = (bf16*)(ws + 0 * SZ_T);
  bf16* Kb  = (bf16*)(ws + 1 * SZ_T);
  bf16* Vb  = (bf16*)(ws + 2 * SZ_T);
  bf16* Att = (bf16*)(ws + 3 * SZ_T);
  bf16* Wqt = (bf16*)(ws + 4 * SZ_T + 0 * SZ_W);
  bf16* Wkt = (bf16*)(ws + 4 * SZ_T + 1 * SZ_W);
  bf16* Wvt = (bf16*)(ws + 4 * SZ_T + 2 * SZ_W);
  bf16* Wot = (bf16*)(ws + 4 * SZ_T + 3 * SZ_W);

  wtrans_kernel<<<dim3(32, 32, 4), dim3(32, 8), 0, stream>>>(Wq, Wk, Wv, Wo, Wqt, Wkt, Wvt, Wot);
  gemm_qkv_kernel<<<dim3(768, 1, 1), 512, 0, stream>>>(
      query, key, value, Wqt, Wkt, Wvt, bq, bk, bv, Qb, Kb, Vb);
  attn_kernel<<<dim3(SEQ / 128, BATCH * NH), 256, 0, stream>>>(Qb, Kb, Vb, Att);
  gemm_out_kernel<<<dim3(256, 1, 1), 512, 0, stream>>>(Att, Wot, bo, out);
}